// Round 1
// baseline (2881.834 us; speedup 1.0000x reference)
//
#include <hip/hip_runtime.h>

#define FIN 128
#define HID 32

// ---------------- degree / norm ----------------

__global__ __launch_bounds__(256) void deg_kernel(const int* __restrict__ dst, int E, int* __restrict__ deg) {
    int e = blockIdx.x * blockDim.x + threadIdx.x;
    if (e < E) atomicAdd(&deg[dst[e]], 1);
}

__global__ __launch_bounds__(256) void dinv_kernel(const int* __restrict__ deg, float* __restrict__ dinv, int n) {
    int i = blockIdx.x * blockDim.x + threadIdx.x;
    // +1.0f accounts for the self-loop the reference concatenates before segment_sum
    if (i < n) dinv[i] = rsqrtf((float)deg[i] + 1.0f);
}

// ---------------- GEMM1: h0 = x @ W1  [n,128]@[128,32] ----------------

__global__ __launch_bounds__(256) void gemm1_kernel(const float* __restrict__ x,
                                                    const float* __restrict__ W,
                                                    float* __restrict__ h0, int n) {
    __shared__ float Ws[FIN * HID];   // 16 KB
    __shared__ float xs[8][FIN];      // 4 KB
    int t = threadIdx.x;
    for (int i = t; i < FIN * HID; i += 256) Ws[i] = W[i];
    int row0 = blockIdx.x * 8;
    {
        int r  = t >> 5;           // 0..7
        int c4 = (t & 31) * 4;     // 0..124
        int row = row0 + r;
        float4 v = (row < n) ? *(const float4*)&x[(size_t)row * FIN + c4]
                             : make_float4(0.f, 0.f, 0.f, 0.f);
        *(float4*)&xs[r][c4] = v;
    }
    __syncthreads();
    int r = t >> 5, col = t & 31;
    int row = row0 + r;
    if (row < n) {
        float acc = 0.f;
        #pragma unroll 16
        for (int k = 0; k < FIN; ++k) acc += xs[r][k] * Ws[k * HID + col];
        h0[(size_t)row * HID + col] = acc;
    }
}

// ---------------- init: acc[i][f] = b[f] + h[i][f] * dinv[i]^2 (self loop) ----------------

__global__ __launch_bounds__(256) void init_acc_kernel(const float* __restrict__ h,
                                                       const float* __restrict__ dinv,
                                                       const float* __restrict__ b,
                                                       float* __restrict__ acc, int n) {
    int t = blockIdx.x * blockDim.x + threadIdx.x;
    if (t < n * HID) {
        int i = t >> 5, f = t & 31;
        float di = dinv[i];
        acc[t] = b[f] + h[t] * di * di;
    }
}

// ---------------- edge scatter: acc[dst] += h[src] * dinv[src]*dinv[dst] ----------------

__global__ __launch_bounds__(256) void edge_kernel(const int* __restrict__ src,
                                                   const int* __restrict__ dst,
                                                   const float* __restrict__ dinv,
                                                   const float* __restrict__ h,
                                                   float* __restrict__ acc, int E) {
    long long t = (long long)blockIdx.x * blockDim.x + threadIdx.x;
    int e = (int)(t >> 3);            // 8 threads per edge, 4 feats each
    if (e >= E) return;
    int f4 = ((int)t & 7) * 4;
    int s = src[e], d = dst[e];
    float nrm = dinv[s] * dinv[d];
    float4 v = *(const float4*)&h[(size_t)s * HID + f4];
    float* a = &acc[(size_t)d * HID + f4];
    unsafeAtomicAdd(a + 0, v.x * nrm);
    unsafeAtomicAdd(a + 1, v.y * nrm);
    unsafeAtomicAdd(a + 2, v.z * nrm);
    unsafeAtomicAdd(a + 3, v.w * nrm);
}

// ---------------- GEMM2 with fused ReLU on input: h2 = relu(acc) @ W2 ----------------

__global__ __launch_bounds__(256) void gemm2_kernel(const float* __restrict__ acc,
                                                    const float* __restrict__ W,
                                                    float* __restrict__ h2, int n) {
    __shared__ float Ws[HID * HID];   // 4 KB
    __shared__ float hs[8][HID];      // 1 KB
    int t = threadIdx.x;
    for (int i = t; i < HID * HID; i += 256) Ws[i] = W[i];
    int row0 = blockIdx.x * 8;
    {
        int r = t >> 5, c = t & 31;
        int row = row0 + r;
        float v = (row < n) ? acc[(size_t)row * HID + c] : 0.f;
        hs[r][c] = fmaxf(v, 0.f);
    }
    __syncthreads();
    int r = t >> 5, col = t & 31;
    int row = row0 + r;
    if (row < n) {
        float s = 0.f;
        #pragma unroll
        for (int k = 0; k < HID; ++k) s += hs[r][k] * Ws[k * HID + col];
        h2[(size_t)row * HID + col] = s;
    }
}

// ---------------- final ReLU in place ----------------

__global__ __launch_bounds__(256) void relu_kernel(float* __restrict__ out, int sz) {
    int t = blockIdx.x * blockDim.x + threadIdx.x;
    if (t < sz) out[t] = fmaxf(out[t], 0.f);
}

extern "C" void kernel_launch(void* const* d_in, const int* in_sizes, int n_in,
                              void* d_out, int out_size, void* d_ws, size_t ws_size,
                              hipStream_t stream) {
    const float* x  = (const float*)d_in[0];
    const int*   ei = (const int*)d_in[1];
    const float* W1 = (const float*)d_in[2];
    const float* b1 = (const float*)d_in[3];
    const float* W2 = (const float*)d_in[4];
    const float* b2 = (const float*)d_in[5];
    float* out = (float*)d_out;

    int n = in_sizes[0] / FIN;      // 100000
    int E = in_sizes[1] / 2;        // 3200000
    const int* src = ei;
    const int* dst = ei + E;

    // workspace layout
    char* ws = (char*)d_ws;
    int*   deg  = (int*)ws;                                        // n ints
    float* dinv = (float*)(ws + (size_t)n * 4);                    // n floats
    float* h0   = (float*)(ws + (size_t)n * 8);                    // n*32 floats
    float* acc  = (float*)(ws + (size_t)n * 8 + (size_t)n * HID * 4); // n*32 floats
    float* h2   = h0;  // reuse h0 buffer for layer-2 features

    hipMemsetAsync(deg, 0, (size_t)n * 4, stream);
    deg_kernel<<<(E + 255) / 256, 256, 0, stream>>>(dst, E, deg);
    dinv_kernel<<<(n + 255) / 256, 256, 0, stream>>>(deg, dinv, n);

    // layer 1
    gemm1_kernel<<<(n + 7) / 8, 256, 0, stream>>>(x, W1, h0, n);
    init_acc_kernel<<<(n * HID + 255) / 256, 256, 0, stream>>>(h0, dinv, b1, acc, n);
    {
        long long threads = (long long)E * 8;
        int blocks = (int)((threads + 255) / 256);
        edge_kernel<<<blocks, 256, 0, stream>>>(src, dst, dinv, h0, acc, E);
    }

    // layer 2 (ReLU of acc fused into gemm2 load)
    gemm2_kernel<<<(n + 7) / 8, 256, 0, stream>>>(acc, W2, h2, n);
    init_acc_kernel<<<(n * HID + 255) / 256, 256, 0, stream>>>(h2, dinv, b2, out, n);
    {
        long long threads = (long long)E * 8;
        int blocks = (int)((threads + 255) / 256);
        edge_kernel<<<blocks, 256, 0, stream>>>(src, dst, dinv, h2, out, E);
    }
    relu_kernel<<<(n * HID + 255) / 256, 256, 0, stream>>>(out, n * HID);
}

// Round 2
// 764.652 us; speedup vs baseline: 3.7688x; 3.7688x over previous
//
#include <hip/hip_runtime.h>

#define FIN 128
#define HID 32
#define SCAN_CHUNK 2048

// ---------------- degree / norm ----------------

__global__ __launch_bounds__(256) void deg_kernel(const int* __restrict__ dst, int E, int* __restrict__ deg) {
    int e = blockIdx.x * blockDim.x + threadIdx.x;
    if (e < E) atomicAdd(&deg[dst[e]], 1);
}

__global__ __launch_bounds__(256) void dinv_kernel(const int* __restrict__ deg, float* __restrict__ dinv, int n) {
    int i = blockIdx.x * blockDim.x + threadIdx.x;
    // +1.0f accounts for the self-loop the reference concatenates before segment_sum
    if (i < n) dinv[i] = rsqrtf((float)deg[i] + 1.0f);
}

// ---------------- exclusive scan of deg -> rowptr (3-kernel hierarchical) ----------------

__global__ __launch_bounds__(256) void scan1_kernel(const int* __restrict__ deg,
                                                    int* __restrict__ rowptr,
                                                    int* __restrict__ chunkSums, int n) {
    __shared__ int lds[256];
    int base = blockIdx.x * SCAN_CHUNK;
    int t = threadIdx.x;
    int v[8];
    int sum = 0;
    #pragma unroll
    for (int j = 0; j < 8; ++j) {
        int idx = base + t * 8 + j;
        v[j] = (idx < n) ? deg[idx] : 0;
        sum += v[j];
    }
    lds[t] = sum;
    __syncthreads();
    for (int off = 1; off < 256; off <<= 1) {
        int x = (t >= off) ? lds[t - off] : 0;
        __syncthreads();
        lds[t] += x;
        __syncthreads();
    }
    int run = (t == 0) ? 0 : lds[t - 1];
    if (t == 255) chunkSums[blockIdx.x] = lds[255];
    #pragma unroll
    for (int j = 0; j < 8; ++j) {
        int idx = base + t * 8 + j;
        if (idx < n) rowptr[idx] = run;
        run += v[j];
    }
}

__global__ __launch_bounds__(64) void scan2_kernel(int* __restrict__ chunkSums, int nChunks) {
    __shared__ int lds[64];
    int t = threadIdx.x;
    int v = (t < nChunks) ? chunkSums[t] : 0;
    lds[t] = v;
    __syncthreads();
    for (int off = 1; off < 64; off <<= 1) {
        int x = (t >= off) ? lds[t - off] : 0;
        __syncthreads();
        lds[t] += x;
        __syncthreads();
    }
    if (t < nChunks) chunkSums[t] = (t == 0) ? 0 : lds[t - 1];
}

__global__ __launch_bounds__(256) void scan3_kernel(int* __restrict__ rowptr,
                                                    int* __restrict__ cursor,
                                                    const int* __restrict__ chunkSums,
                                                    int n, int E) {
    int i = blockIdx.x * blockDim.x + threadIdx.x;
    if (i < n) {
        int r = rowptr[i] + chunkSums[i / SCAN_CHUNK];
        rowptr[i] = r;
        cursor[i] = r;
    }
    if (i == n) rowptr[n] = E;
}

// ---------------- pack edges into CSR buckets by dst ----------------

__global__ __launch_bounds__(256) void pack_kernel(const int* __restrict__ src,
                                                   const int* __restrict__ dst,
                                                   int* __restrict__ cursor,
                                                   int* __restrict__ csr_src, int E) {
    int e = blockIdx.x * blockDim.x + threadIdx.x;
    if (e < E) {
        int d = dst[e];
        int pos = atomicAdd(&cursor[d], 1);
        csr_src[pos] = src[e];
    }
}

// ---------------- GEMM1: h0 = x @ W1  [n,128]@[128,32] ----------------

__global__ __launch_bounds__(256) void gemm1_kernel(const float* __restrict__ x,
                                                    const float* __restrict__ W,
                                                    float* __restrict__ h0, int n) {
    __shared__ float Ws[FIN * HID];   // 16 KB
    __shared__ float xs[8][FIN];      // 4 KB
    int t = threadIdx.x;
    for (int i = t; i < FIN * HID; i += 256) Ws[i] = W[i];
    int row0 = blockIdx.x * 8;
    {
        int r  = t >> 5;
        int c4 = (t & 31) * 4;
        int row = row0 + r;
        float4 v = (row < n) ? *(const float4*)&x[(size_t)row * FIN + c4]
                             : make_float4(0.f, 0.f, 0.f, 0.f);
        *(float4*)&xs[r][c4] = v;
    }
    __syncthreads();
    int r = t >> 5, col = t & 31;
    int row = row0 + r;
    if (row < n) {
        float acc = 0.f;
        #pragma unroll 16
        for (int k = 0; k < FIN; ++k) acc += xs[r][k] * Ws[k * HID + col];
        h0[(size_t)row * HID + col] = acc;
    }
}

// ---------------- gather-aggregate: out[i] = b + h[i]*di^2 + sum_e h[src]*dinv[src]*di ----------------

__global__ __launch_bounds__(256) void gather_kernel(const int* __restrict__ rowptr,
                                                     const int* __restrict__ csr_src,
                                                     const float* __restrict__ dinv,
                                                     const float* __restrict__ h,
                                                     const float* __restrict__ bias,
                                                     float* __restrict__ out, int n, int relu) {
    int g = threadIdx.x >> 5, f = threadIdx.x & 31;
    int i = blockIdx.x * 8 + g;
    if (i >= n) return;
    float di = dinv[i];
    float acc = bias[f] + h[(size_t)i * HID + f] * di * di;
    int beg = rowptr[i], end = rowptr[i + 1];
    // process edges in batches of 32: coalesced src load, broadcast via shfl
    for (int base = beg; base < end; base += 32) {
        int idx = base + f;
        int sv = (idx < end) ? csr_src[idx] : 0;
        int cnt = min(end - base, 32);
        #pragma unroll 4
        for (int j = 0; j < cnt; ++j) {
            int s = __shfl(sv, j, 32);
            acc += h[(size_t)s * HID + f] * (dinv[s] * di);
        }
    }
    if (relu) acc = fmaxf(acc, 0.f);
    out[(size_t)i * HID + f] = acc;
}

// ---------------- GEMM2 with fused ReLU on input: h2 = relu(acc) @ W2 ----------------

__global__ __launch_bounds__(256) void gemm2_kernel(const float* __restrict__ acc,
                                                    const float* __restrict__ W,
                                                    float* __restrict__ h2, int n) {
    __shared__ float Ws[HID * HID];
    __shared__ float hs[8][HID];
    int t = threadIdx.x;
    for (int i = t; i < HID * HID; i += 256) Ws[i] = W[i];
    int row0 = blockIdx.x * 8;
    {
        int r = t >> 5, c = t & 31;
        int row = row0 + r;
        float v = (row < n) ? acc[(size_t)row * HID + c] : 0.f;
        hs[r][c] = fmaxf(v, 0.f);
    }
    __syncthreads();
    int r = t >> 5, col = t & 31;
    int row = row0 + r;
    if (row < n) {
        float s = 0.f;
        #pragma unroll
        for (int k = 0; k < HID; ++k) s += hs[r][k] * Ws[k * HID + col];
        h2[(size_t)row * HID + col] = s;
    }
}

extern "C" void kernel_launch(void* const* d_in, const int* in_sizes, int n_in,
                              void* d_out, int out_size, void* d_ws, size_t ws_size,
                              hipStream_t stream) {
    const float* x  = (const float*)d_in[0];
    const int*   ei = (const int*)d_in[1];
    const float* W1 = (const float*)d_in[2];
    const float* b1 = (const float*)d_in[3];
    const float* W2 = (const float*)d_in[4];
    const float* b2 = (const float*)d_in[5];
    float* out = (float*)d_out;

    int n = in_sizes[0] / FIN;      // 100000
    int E = in_sizes[1] / 2;        // 3200000
    const int* src = ei;
    const int* dst = ei + E;

    int nChunks = (n + SCAN_CHUNK - 1) / SCAN_CHUNK;   // 49

    // workspace layout (all 256-B aligned)
    char* ws = (char*)d_ws;
    size_t off = 0;
    auto alloc = [&](size_t bytes) { char* p = ws + off; off += (bytes + 255) & ~(size_t)255; return p; };
    int*   deg       = (int*)alloc((size_t)n * 4);
    float* dinv      = (float*)alloc((size_t)n * 4);
    int*   rowptr    = (int*)alloc(((size_t)n + 1) * 4);
    int*   cursor    = (int*)alloc((size_t)n * 4);
    int*   chunkSums = (int*)alloc((size_t)nChunks * 4);
    int*   csr_src   = (int*)alloc((size_t)E * 4);
    float* h0        = (float*)alloc((size_t)n * HID * 4);
    float* acc       = (float*)alloc((size_t)n * HID * 4);
    float* h2        = h0;   // reuse

    // ---- graph preprocessing ----
    hipMemsetAsync(deg, 0, (size_t)n * 4, stream);
    deg_kernel<<<(E + 255) / 256, 256, 0, stream>>>(dst, E, deg);
    dinv_kernel<<<(n + 255) / 256, 256, 0, stream>>>(deg, dinv, n);
    scan1_kernel<<<nChunks, 256, 0, stream>>>(deg, rowptr, chunkSums, n);
    scan2_kernel<<<1, 64, 0, stream>>>(chunkSums, nChunks);
    scan3_kernel<<<(n + 256) / 256, 256, 0, stream>>>(rowptr, cursor, chunkSums, n, E);
    pack_kernel<<<(E + 255) / 256, 256, 0, stream>>>(src, dst, cursor, csr_src, E);

    // ---- layer 1 ----
    gemm1_kernel<<<(n + 7) / 8, 256, 0, stream>>>(x, W1, h0, n);
    gather_kernel<<<(n + 7) / 8, 256, 0, stream>>>(rowptr, csr_src, dinv, h0, b1, acc, n, 0);

    // ---- layer 2 ----
    gemm2_kernel<<<(n + 7) / 8, 256, 0, stream>>>(acc, W2, h2, n);
    gather_kernel<<<(n + 7) / 8, 256, 0, stream>>>(rowptr, csr_src, dinv, h2, b2, out, n, 1);
}